// Round 1
// baseline (60.971 us; speedup 1.0000x reference)
//
#include <hip/hip_runtime.h>
#include <math.h>

#define HIDDEN 1024
#define VOCAB 50257

__device__ __forceinline__ float wave_reduce_sum(float v) {
#pragma unroll
    for (int m = 1; m < 64; m <<= 1) v += __shfl_xor(v, m, 64);
    return v;
}

// K1: GRU gates + h_new. One wave per hidden unit j (1024 waves total).
__global__ __launch_bounds__(256) void gru_kernel(
    const int* token_p, const float* hidden, const float* emb,
    const float* w_ih, const float* w_hh, const float* b_ih, const float* b_hh,
    float* h_new_out) {
    const int wave = threadIdx.x >> 6;
    const int lane = threadIdx.x & 63;
    const int j = blockIdx.x * 4 + wave;  // 0..1023

    const int token = token_p[0];  // int64 little-endian low word also works
    const float4* x4 = (const float4*)(emb + (size_t)token * HIDDEN);
    const float4* h4 = (const float4*)hidden;

    float4 xs[4], hs[4];
#pragma unroll
    for (int k = 0; k < 4; ++k) {
        const int idx = k * 64 + lane;
        float4 e = x4[idx];
        xs[k] = make_float4(fmaxf(e.x, 0.f), fmaxf(e.y, 0.f),
                            fmaxf(e.z, 0.f), fmaxf(e.w, 0.f));
        hs[k] = h4[idx];
    }

    float acc[6] = {0.f, 0.f, 0.f, 0.f, 0.f, 0.f};
#pragma unroll
    for (int g = 0; g < 3; ++g) {
        const float4* wi = (const float4*)(w_ih + (size_t)(g * HIDDEN + j) * HIDDEN);
        const float4* wh = (const float4*)(w_hh + (size_t)(g * HIDDEN + j) * HIDDEN);
#pragma unroll
        for (int k = 0; k < 4; ++k) {
            const int idx = k * 64 + lane;
            float4 a = wi[idx];
            float4 b = wh[idx];
            acc[g]     += a.x * xs[k].x + a.y * xs[k].y + a.z * xs[k].z + a.w * xs[k].w;
            acc[3 + g] += b.x * hs[k].x + b.y * hs[k].y + b.z * hs[k].z + b.w * hs[k].w;
        }
    }
#pragma unroll
    for (int q = 0; q < 6; ++q) acc[q] = wave_reduce_sum(acc[q]);

    if (lane == 0) {
        const float i_r = acc[0] + b_ih[j];
        const float i_z = acc[1] + b_ih[HIDDEN + j];
        const float i_n = acc[2] + b_ih[2 * HIDDEN + j];
        const float h_r = acc[3] + b_hh[j];
        const float h_z = acc[4] + b_hh[HIDDEN + j];
        const float h_n = acc[5] + b_hh[2 * HIDDEN + j];
        const float r = 1.f / (1.f + expf(-(i_r + h_r)));
        const float z = 1.f / (1.f + expf(-(i_z + h_z)));
        const float n = tanhf(i_n + r * h_n);
        h_new_out[j] = (1.f - z) * n + z * hidden[j];
    }
}

// K2: logits[v] = h_new . w_out[v] + b_out[v]. One wave per vocab row.
__global__ __launch_bounds__(256) void logits_kernel(
    const float* __restrict__ h_new, const float* __restrict__ w_out,
    const float* __restrict__ b_out, float* __restrict__ logits) {
    const int wave = threadIdx.x >> 6;
    const int lane = threadIdx.x & 63;
    const int v = blockIdx.x * 4 + wave;
    if (v >= VOCAB) return;

    const float4* h4 = (const float4*)h_new;
    float4 hs[4];
#pragma unroll
    for (int k = 0; k < 4; ++k) hs[k] = h4[k * 64 + lane];

    const float4* w4 = (const float4*)(w_out + (size_t)v * HIDDEN);
    float acc = 0.f;
#pragma unroll
    for (int k = 0; k < 4; ++k) {
        float4 w = w4[k * 64 + lane];
        acc += w.x * hs[k].x + w.y * hs[k].y + w.z * hs[k].z + w.w * hs[k].w;
    }
    acc = wave_reduce_sum(acc);
    if (lane == 0) logits[v] = acc + b_out[v];
}

// K3: single-block max + log-sum-exp over VOCAB logits.
__global__ __launch_bounds__(1024) void softmax_reduce_kernel(
    const float* __restrict__ logits, float* __restrict__ scalars) {
    __shared__ float red[1024];
    const int t = threadIdx.x;

    float m = -INFINITY;
    for (int i = t; i < VOCAB; i += 1024) m = fmaxf(m, logits[i]);
    red[t] = m;
    __syncthreads();
    for (int s = 512; s > 0; s >>= 1) {
        if (t < s) red[t] = fmaxf(red[t], red[t + s]);
        __syncthreads();
    }
    m = red[0];
    __syncthreads();

    float sum = 0.f;
    for (int i = t; i < VOCAB; i += 1024) sum += expf(logits[i] - m);
    red[t] = sum;
    __syncthreads();
    for (int s = 512; s > 0; s >>= 1) {
        if (t < s) red[t] += red[t + s];
        __syncthreads();
    }
    if (t == 0) scalars[0] = m + logf(red[0]);
}

// K4: logp[i] = logits[i] - (m + lse), in place in d_out.
__global__ __launch_bounds__(256) void logp_kernel(
    float* __restrict__ logits, const float* __restrict__ scalars) {
    const int i = blockIdx.x * blockDim.x + threadIdx.x;
    if (i < VOCAB) logits[i] -= scalars[0];
}

extern "C" void kernel_launch(void* const* d_in, const int* in_sizes, int n_in,
                              void* d_out, int out_size, void* d_ws, size_t ws_size,
                              hipStream_t stream) {
    const int*   token  = (const int*)d_in[0];
    const float* hidden = (const float*)d_in[1];
    const float* emb    = (const float*)d_in[2];
    const float* w_ih   = (const float*)d_in[3];
    const float* w_hh   = (const float*)d_in[4];
    const float* b_ih   = (const float*)d_in[5];
    const float* b_hh   = (const float*)d_in[6];
    const float* w_out  = (const float*)d_in[7];
    const float* b_out  = (const float*)d_in[8];

    float* out    = (float*)d_out;         // [0..VOCAB) = logp, [VOCAB..VOCAB+HIDDEN) = h_new
    float* h_new  = out + VOCAB;
    float* logits = out;                   // computed in place, then shifted by K4
    float* scalars = (float*)d_ws;         // 1 float: m + lse

    // K1: 1024 hidden units, 4 waves/block -> 256 blocks
    gru_kernel<<<HIDDEN / 4, 256, 0, stream>>>(token, hidden, emb, w_ih, w_hh,
                                               b_ih, b_hh, h_new);
    // K2: one wave per vocab row
    logits_kernel<<<(VOCAB + 3) / 4, 256, 0, stream>>>(h_new, w_out, b_out, logits);
    // K3: single-block reduction
    softmax_reduce_kernel<<<1, 1024, 0, stream>>>(logits, scalars);
    // K4: subtract log-sum-exp
    logp_kernel<<<(VOCAB + 255) / 256, 256, 0, stream>>>(logits, scalars);
}

// Round 2
// 46.866 us; speedup vs baseline: 1.3010x; 1.3010x over previous
//
#include <hip/hip_runtime.h>
#include <math.h>

#define HIDDEN 1024
#define VOCAB 50257
#define K2_BLOCKS 1024
#define K2_WAVES (K2_BLOCKS * 4)

__device__ __forceinline__ float wave_reduce_sum(float v) {
#pragma unroll
    for (int m = 1; m < 64; m <<= 1) v += __shfl_xor(v, m, 64);
    return v;
}

// K1: GRU gates + h_new. One block per hidden unit j, one wave per gate g.
__global__ __launch_bounds__(192) void gru_kernel(
    const int* token_p, const float* __restrict__ hidden, const float* __restrict__ emb,
    const float* __restrict__ w_ih, const float* __restrict__ w_hh,
    const float* __restrict__ b_ih, const float* __restrict__ b_hh,
    float* __restrict__ h_new_out) {
    const int g = threadIdx.x >> 6;       // gate 0..2 (r, z, n)
    const int lane = threadIdx.x & 63;
    const int j = blockIdx.x;             // 0..1023

    const int token = token_p[0];         // low 32 bits of the int64 token
    const float4* x4 = (const float4*)(emb + (size_t)token * HIDDEN);
    const float4* h4 = (const float4*)hidden;

    const float4* wi = (const float4*)(w_ih + (size_t)(g * HIDDEN + j) * HIDDEN);
    const float4* wh = (const float4*)(w_hh + (size_t)(g * HIDDEN + j) * HIDDEN);

    float acc_i = 0.f, acc_h = 0.f;
#pragma unroll
    for (int k = 0; k < 4; ++k) {
        const int idx = k * 64 + lane;
        float4 e = x4[idx];
        float4 h = h4[idx];
        float4 a = wi[idx];
        float4 b = wh[idx];
        e.x = fmaxf(e.x, 0.f); e.y = fmaxf(e.y, 0.f);
        e.z = fmaxf(e.z, 0.f); e.w = fmaxf(e.w, 0.f);
        acc_i += a.x * e.x + a.y * e.y + a.z * e.z + a.w * e.w;
        acc_h += b.x * h.x + b.y * h.y + b.z * h.z + b.w * h.w;
    }
    acc_i = wave_reduce_sum(acc_i);
    acc_h = wave_reduce_sum(acc_h);

    __shared__ float red_i[3], red_h[3];
    if (lane == 0) { red_i[g] = acc_i; red_h[g] = acc_h; }
    __syncthreads();

    if (threadIdx.x == 0) {
        const float i_r = red_i[0] + b_ih[j];
        const float i_z = red_i[1] + b_ih[HIDDEN + j];
        const float i_n = red_i[2] + b_ih[2 * HIDDEN + j];
        const float h_r = red_h[0] + b_hh[j];
        const float h_z = red_h[1] + b_hh[HIDDEN + j];
        const float h_n = red_h[2] + b_hh[2 * HIDDEN + j];
        const float r = 1.f / (1.f + expf(-(i_r + h_r)));
        const float z = 1.f / (1.f + expf(-(i_z + h_z)));
        const float n = tanhf(i_n + r * h_n);
        h_new_out[j] = (1.f - z) * n + z * hidden[j];
    }
}

// K2: logits[v] = h_new . w_out[v] + b_out[v], grid-strided one wave per row,
// with fused per-block online (max, sumexp) partials.
__global__ __launch_bounds__(256) void logits_kernel(
    const float* __restrict__ h_new, const float* __restrict__ w_out,
    const float* __restrict__ b_out, float* __restrict__ logits,
    float* __restrict__ partials) {
    const int wave = threadIdx.x >> 6;
    const int lane = threadIdx.x & 63;
    const int gw = blockIdx.x * 4 + wave;   // 0..K2_WAVES-1

    const float4* h4 = (const float4*)h_new;
    float4 hs[4];
#pragma unroll
    for (int k = 0; k < 4; ++k) hs[k] = h4[k * 64 + lane];

    float m = -INFINITY, s = 0.f;
    for (int v = gw; v < VOCAB; v += K2_WAVES) {
        const float4* w4 = (const float4*)(w_out + (size_t)v * HIDDEN);
        float acc = 0.f;
#pragma unroll
        for (int k = 0; k < 4; ++k) {
            float4 w = w4[k * 64 + lane];
            acc += w.x * hs[k].x + w.y * hs[k].y + w.z * hs[k].z + w.w * hs[k].w;
        }
        acc = wave_reduce_sum(acc);
        const float l = acc + b_out[v];
        if (lane == 0) logits[v] = l;
        // online max/sum-exp, wave-uniform (replicated on all lanes)
        if (l > m) { s *= expf(m - l); m = l; }
        s += expf(l - m);
    }

    __shared__ float sm[4], ss[4];
    if (lane == 0) { sm[wave] = m; ss[wave] = s; }
    __syncthreads();
    if (threadIdx.x == 0) {
        float M = fmaxf(fmaxf(sm[0], sm[1]), fmaxf(sm[2], sm[3]));
        float S = ss[0] * expf(sm[0] - M) + ss[1] * expf(sm[1] - M) +
                  ss[2] * expf(sm[2] - M) + ss[3] * expf(sm[3] - M);
        partials[2 * blockIdx.x]     = M;
        partials[2 * blockIdx.x + 1] = S;
    }
}

// K3: combine K2_BLOCKS (m, s) pairs -> scalars[0] = M + log(sum s_b * exp(m_b - M)).
__global__ __launch_bounds__(1024) void lse_combine_kernel(
    const float* __restrict__ partials, float* __restrict__ scalars) {
    const int t = threadIdx.x;   // exactly K2_BLOCKS threads
    __shared__ float red[1024];

    const float m = partials[2 * t];
    const float s = partials[2 * t + 1];

    red[t] = m;
    __syncthreads();
    for (int st = 512; st > 0; st >>= 1) {
        if (t < st) red[t] = fmaxf(red[t], red[t + st]);
        __syncthreads();
    }
    const float M = red[0];
    __syncthreads();

    red[t] = s * expf(m - M);
    __syncthreads();
    for (int st = 512; st > 0; st >>= 1) {
        if (t < st) red[t] += red[t + st];
        __syncthreads();
    }
    if (t == 0) scalars[0] = M + logf(red[0]);
}

// K4: logp[i] = logits[i] - (m + lse), in place in d_out.
__global__ __launch_bounds__(256) void logp_kernel(
    float* __restrict__ logits, const float* __restrict__ scalars) {
    const int i = blockIdx.x * blockDim.x + threadIdx.x;
    if (i < VOCAB) logits[i] -= scalars[0];
}

extern "C" void kernel_launch(void* const* d_in, const int* in_sizes, int n_in,
                              void* d_out, int out_size, void* d_ws, size_t ws_size,
                              hipStream_t stream) {
    const int*   token  = (const int*)d_in[0];
    const float* hidden = (const float*)d_in[1];
    const float* emb    = (const float*)d_in[2];
    const float* w_ih   = (const float*)d_in[3];
    const float* w_hh   = (const float*)d_in[4];
    const float* b_ih   = (const float*)d_in[5];
    const float* b_hh   = (const float*)d_in[6];
    const float* w_out  = (const float*)d_in[7];
    const float* b_out  = (const float*)d_in[8];

    float* out     = (float*)d_out;        // [0..VOCAB) = logp, [VOCAB..+HIDDEN) = h_new
    float* h_new   = out + VOCAB;
    float* logits  = out;                  // computed in place, then shifted by K4
    float* ws      = (float*)d_ws;
    float* partials = ws;                  // 2 * K2_BLOCKS floats
    float* scalars  = ws + 2 * K2_BLOCKS;  // 1 float: m + lse

    gru_kernel<<<HIDDEN, 192, 0, stream>>>(token, hidden, emb, w_ih, w_hh,
                                           b_ih, b_hh, h_new);
    logits_kernel<<<K2_BLOCKS, 256, 0, stream>>>(h_new, w_out, b_out, logits, partials);
    lse_combine_kernel<<<1, 1024, 0, stream>>>(partials, scalars);
    logp_kernel<<<(VOCAB + 255) / 256, 256, 0, stream>>>(logits, scalars);
}